// Round 1
// baseline (582.954 us; speedup 1.0000x reference)
//
#include <hip/hip_runtime.h>
#include <hip/hip_bf16.h>

using bf16 = __hip_bfloat16;
typedef short bf16x8v __attribute__((ext_vector_type(8)));
typedef float f32x4v  __attribute__((ext_vector_type(4)));

#define GLD_LDS16(g, l) __builtin_amdgcn_global_load_lds(                      \
    (const __attribute__((address_space(1))) void*)(g),                        \
    (__attribute__((address_space(3))) void*)(l), 16, 0, 0)

// ---------------------------------------------------------------- fp32->bf16
__global__ void f2b4(const float* __restrict__ s, bf16* __restrict__ d, int n4) {
  int i = blockIdx.x * blockDim.x + threadIdx.x;
  if (i >= n4) return;
  const float4 f = reinterpret_cast<const float4*>(s)[i];
  struct B4 { bf16 a, b, c, d; };
  B4 o = { __float2bfloat16(f.x), __float2bfloat16(f.y),
           __float2bfloat16(f.z), __float2bfloat16(f.w) };
  reinterpret_cast<B4*>(d)[i] = o;
}

// ------------------------------------------------------- bf16 MFMA GEMM (NT)
// out[m][n] = sum_k A[m][k] * W[n][k],  M = 32768 (grid.x*128), N = 768, K = 768
// m97 structure: 128x128 tile, BK=32, global_load_lds width16, 16x16x32 MFMA.
__global__ __launch_bounds__(256) void gemm_nt(
    const bf16* __restrict__ A, const bf16* __restrict__ W,
    float* __restrict__ outF, bf16* __restrict__ outB, int sigm)
{
  __shared__ __align__(16) bf16 lds_a[128 * 32];
  __shared__ __align__(16) bf16 lds_b[128 * 32];
  const int tid  = threadIdx.x;
  const size_t m0 = (size_t)blockIdx.x * 128;
  const int n0   = blockIdx.y * 128;
  const int lane = tid & 63;
  const int wave = tid >> 6;
  const int quad = lane >> 4;
  const int l15  = lane & 15;
  const int wr   = (wave >> 1) * 64;   // wave's 64x64 sub-tile
  const int wc   = (wave & 1) * 64;

  // staging slots: slot s -> row s>>2, col (s&3)*8 ; thread stages s=tid, tid+256
  const int r0 = tid >> 2;
  const int c0 = (tid & 3) * 8;

  f32x4v acc[4][4];
#pragma unroll
  for (int i = 0; i < 4; ++i)
#pragma unroll
    for (int j = 0; j < 4; ++j)
#pragma unroll
      for (int r = 0; r < 4; ++r) acc[i][j][r] = 0.0f;

  for (int k0 = 0; k0 < 768; k0 += 32) {
    __syncthreads();
    GLD_LDS16(A + (m0 + r0) * 768 + k0 + c0,               &lds_a[(size_t)tid * 8]);
    GLD_LDS16(A + (m0 + r0 + 64) * 768 + k0 + c0,          &lds_a[(size_t)(tid + 256) * 8]);
    GLD_LDS16(W + (size_t)(n0 + r0) * 768 + k0 + c0,       &lds_b[(size_t)tid * 8]);
    GLD_LDS16(W + (size_t)(n0 + r0 + 64) * 768 + k0 + c0,  &lds_b[(size_t)(tid + 256) * 8]);
    __syncthreads();

    bf16x8v av[4], bv[4];
#pragma unroll
    for (int i = 0; i < 4; ++i)
      av[i] = *(const bf16x8v*)&lds_a[(wr + 16 * i + l15) * 32 + quad * 8];
#pragma unroll
    for (int j = 0; j < 4; ++j)
      bv[j] = *(const bf16x8v*)&lds_b[(wc + 16 * j + l15) * 32 + quad * 8];
#pragma unroll
    for (int i = 0; i < 4; ++i)
#pragma unroll
      for (int j = 0; j < 4; ++j)
        acc[i][j] = __builtin_amdgcn_mfma_f32_16x16x32_bf16(av[i], bv[j], acc[i][j], 0, 0, 0);
  }

  // epilogue: D row = quad*4 + r, col = l15 within each 16x16 tile  (m89-verified)
#pragma unroll
  for (int i = 0; i < 4; ++i) {
    const size_t mrow = m0 + wr + 16 * i + quad * 4;
#pragma unroll
    for (int j = 0; j < 4; ++j) {
      const int col = n0 + wc + 16 * j + l15;
#pragma unroll
      for (int r = 0; r < 4; ++r) {
        float val = acc[i][j][r];
        const size_t off = (mrow + r) * 768 + col;
        if (outF) {
          outF[off] = val;
        } else {
          if (sigm) val = 1.0f / (1.0f + __expf(-val));
          outB[off] = __float2bfloat16(val);
        }
      }
    }
  }
}

// ------------------------------------------------------------ WKV chunk scan
// G=64 chunks of L=64.  State (aa,bb,pp); value = (aa,bb)*e^pp.
__global__ void wkv_phaseA(const float* __restrict__ K, const float* __restrict__ V,
                           const float* __restrict__ sd,
                           float* __restrict__ sA, float* __restrict__ sB, float* __restrict__ sP)
{
  const int idx = blockIdx.x * 256 + threadIdx.x;   // B*G*C = 393216
  const int c  = idx % 768;
  const int bg = idx / 768;
  const int g  = bg & 63;
  const int b  = bg >> 6;
  const float w = sd[c] * (1.0f / 4096.0f);
  float aa = 0.f, bb = 0.f, pp = -1e38f;
  const size_t base = ((size_t)b * 4096 + (size_t)g * 64) * 768 + c;
#pragma unroll 4
  for (int t = 0; t < 64; ++t) {
    const float kt = K[base + (size_t)t * 768];
    const float vt = V[base + (size_t)t * 768];
    const float ww2 = w + pp;
    const float p2  = fmaxf(ww2, kt);
    const float e1b = __expf(ww2 - p2);
    const float e2b = __expf(kt - p2);
    aa = e1b * aa + e2b * vt;
    bb = e1b * bb + e2b;
    pp = p2;
  }
  const int o = g * 6144 + b * 768 + c;
  sA[o] = aa; sB[o] = bb; sP[o] = pp;
}

__global__ void wkv_phaseB(const float* __restrict__ sA, const float* __restrict__ sB,
                           const float* __restrict__ sP,
                           float* __restrict__ iA, float* __restrict__ iB, float* __restrict__ iP,
                           const float* __restrict__ sd)
{
  const int bc = blockIdx.x * 256 + threadIdx.x;    // B*C = 6144
  const int c  = bc % 768;
  const float Lw = 64.0f * (sd[c] * (1.0f / 4096.0f));
  float aa = 0.f, bb = 0.f, pp = -1e38f;
  for (int g = 0; g < 64; ++g) {
    const int o = g * 6144 + bc;
    iA[o] = aa; iB[o] = bb; iP[o] = pp;             // state BEFORE chunk g
    const float la = sA[o], lb = sB[o], lp = sP[o];
    const float pd = pp + Lw;
    const float pn = fmaxf(pd, lp);
    const float e0 = __expf(pd - pn);
    const float e1 = __expf(lp - pn);
    aa = e0 * aa + e1 * la;
    bb = e0 * bb + e1 * lb;
    pp = pn;
  }
}

__global__ void wkv_phaseC(const float* __restrict__ K, const float* __restrict__ V,
                           const bf16* __restrict__ SR,
                           const float* __restrict__ iA, const float* __restrict__ iB,
                           const float* __restrict__ iP,
                           const float* __restrict__ sd, const float* __restrict__ sf,
                           bf16* __restrict__ RY)
{
  const int idx = blockIdx.x * 256 + threadIdx.x;
  const int c  = idx % 768;
  const int bg = idx / 768;
  const int g  = bg & 63;
  const int b  = bg >> 6;
  const float w = sd[c] * (1.0f / 4096.0f);
  const float u = sf[c] * (1.0f / 4096.0f);
  const int o = g * 6144 + b * 768 + c;
  float aa = iA[o], bb = iB[o], pp = iP[o];
  const size_t base = ((size_t)b * 4096 + (size_t)g * 64) * 768 + c;
#pragma unroll 4
  for (int t = 0; t < 64; ++t) {
    const float kt = K[base + (size_t)t * 768];
    const float vt = V[base + (size_t)t * 768];
    // faithful per-step ops of the reference
    const float ww = u + kt;
    const float p  = fmaxf(pp, ww);
    const float e1 = __expf(pp - p);
    const float e2 = __expf(ww - p);
    const float y  = (e1 * aa + e2 * vt) / (e1 * bb + e2);
    const float s  = __bfloat162float(SR[base + (size_t)t * 768]);
    RY[base + (size_t)t * 768] = __float2bfloat16(s * y);
    const float ww2 = w + pp;
    const float p2  = fmaxf(ww2, kt);
    const float e1b = __expf(ww2 - p2);
    const float e2b = __expf(kt - p2);
    aa = e1b * aa + e2b * vt;
    bb = e1b * bb + e2b;
    pp = p2;
  }
}

// ---------------------------------------------------------------------------
extern "C" void kernel_launch(void* const* d_in, const int* in_sizes, int n_in,
                              void* d_out, int out_size, void* d_ws, size_t ws_size,
                              hipStream_t stream)
{
  const float* x  = (const float*)d_in[0];
  const float* wk = (const float*)d_in[1];
  const float* wv = (const float*)d_in[2];
  const float* wr = (const float*)d_in[3];
  const float* wo = (const float*)d_in[4];
  const float* sd = (const float*)d_in[5];
  const float* sf = (const float*)d_in[6];
  float* out = (float*)d_out;

  char* ws = (char*)d_ws;
  // workspace layout (316,145,664 bytes total)
  bf16*  x_bf  = (bf16*) (ws + 0);            // 25165824 * 2
  bf16*  wk_bf = (bf16*) (ws + 50331648);     // 589824 * 2
  bf16*  wv_bf = (bf16*) (ws + 51511296);
  bf16*  wr_bf = (bf16*) (ws + 52690944);
  bf16*  wo_bf = (bf16*) (ws + 53870592);
  float* Kf    = (float*)(ws + 55050240);     // 25165824 * 4
  float* Vf    = (float*)(ws + 155713536);
  bf16*  sr_bf = (bf16*) (ws + 256376832);    // 25165824 * 2
  float* sumA  = (float*)(ws + 306708480);    // 64*6144 * 4 each
  float* sumB  = (float*)(ws + 308281344);
  float* sumP  = (float*)(ws + 309854208);
  float* iniA  = (float*)(ws + 311427072);
  float* iniB  = (float*)(ws + 312999936);
  float* iniP  = (float*)(ws + 314572800);
  bf16*  ry_bf = x_bf;                        // x dead after GEMM1 -> alias

  f2b4<<<24576, 256, 0, stream>>>(x,  x_bf,  6291456);
  f2b4<<<576,   256, 0, stream>>>(wk, wk_bf, 147456);
  f2b4<<<576,   256, 0, stream>>>(wv, wv_bf, 147456);
  f2b4<<<576,   256, 0, stream>>>(wr, wr_bf, 147456);
  f2b4<<<576,   256, 0, stream>>>(wo, wo_bf, 147456);

  dim3 gg(256, 6);
  gemm_nt<<<gg, 256, 0, stream>>>(x_bf, wk_bf, Kf, nullptr, 0);
  gemm_nt<<<gg, 256, 0, stream>>>(x_bf, wv_bf, Vf, nullptr, 0);
  gemm_nt<<<gg, 256, 0, stream>>>(x_bf, wr_bf, nullptr, sr_bf, 1);

  wkv_phaseA<<<1536, 256, 0, stream>>>(Kf, Vf, sd, sumA, sumB, sumP);
  wkv_phaseB<<<24,   256, 0, stream>>>(sumA, sumB, sumP, iniA, iniB, iniP, sd);
  wkv_phaseC<<<1536, 256, 0, stream>>>(Kf, Vf, sr_bf, iniA, iniB, iniP, sd, sf, ry_bf);

  gemm_nt<<<gg, 256, 0, stream>>>(ry_bf, wo_bf, out, nullptr, 0);
}

// Round 2
// 501.059 us; speedup vs baseline: 1.1634x; 1.1634x over previous
//
#include <hip/hip_runtime.h>
#include <hip/hip_bf16.h>

using bf16 = __hip_bfloat16;
typedef short bf16x8v __attribute__((ext_vector_type(8)));
typedef float f32x4v  __attribute__((ext_vector_type(4)));

#define GLD_LDS16(g, l) __builtin_amdgcn_global_load_lds(                      \
    (const __attribute__((address_space(1))) void*)(g),                        \
    (__attribute__((address_space(3))) void*)(l), 16, 0, 0)

// ---------------------------------------------------------------- fp32->bf16
__global__ void f2b4(const float* __restrict__ s, bf16* __restrict__ d, int n4) {
  int i = blockIdx.x * blockDim.x + threadIdx.x;
  if (i >= n4) return;
  const float4 f = reinterpret_cast<const float4*>(s)[i];
  struct B4 { bf16 a, b, c, d; };
  B4 o = { __float2bfloat16(f.x), __float2bfloat16(f.y),
           __float2bfloat16(f.z), __float2bfloat16(f.w) };
  reinterpret_cast<B4*>(d)[i] = o;
}

// --------------------------------------------------------------- GEMM core
// 128x128 tile, BK=32, global_load_lds width16, 16x16x32 MFMA.
// LDS XOR swizzle: 16B-granule g of row r stored at slot granule g ^ ((r>>1)&3)
// -> wave64 ds_read_b128 spreads over all 8 bank-granules 2-way (free).
__device__ __forceinline__ void gemm_tile_acc(
    const bf16* __restrict__ A, const bf16* __restrict__ W,
    bf16* lds_a, bf16* lds_b, int tid, size_t m0, int n0, f32x4v acc[4][4])
{
  const int lane = tid & 63;
  const int wave = tid >> 6;
  const int quad = lane >> 4;
  const int l15  = lane & 15;
  const int wr   = (wave >> 1) * 64;
  const int wc   = (wave & 1) * 64;

  const int r0 = tid >> 2;                       // staged row (0..63), +64 second slot
  const int g  = tid & 3;                        // granule within row
  const int c0 = ((g ^ ((r0 >> 1) & 3)) * 8);    // swizzled k-offset (elements)
  // note: swz(r0+64) == swz(r0), so both slots use the same c0

#pragma unroll
  for (int i = 0; i < 4; ++i)
#pragma unroll
    for (int j = 0; j < 4; ++j)
#pragma unroll
      for (int r = 0; r < 4; ++r) acc[i][j][r] = 0.0f;

  for (int k0 = 0; k0 < 768; k0 += 32) {
    __syncthreads();
    GLD_LDS16(A + (m0 + r0) * 768 + k0 + c0,               &lds_a[(size_t)tid * 8]);
    GLD_LDS16(A + (m0 + r0 + 64) * 768 + k0 + c0,          &lds_a[(size_t)(tid + 256) * 8]);
    GLD_LDS16(W + (size_t)(n0 + r0) * 768 + k0 + c0,       &lds_b[(size_t)tid * 8]);
    GLD_LDS16(W + (size_t)(n0 + r0 + 64) * 768 + k0 + c0,  &lds_b[(size_t)(tid + 256) * 8]);
    __syncthreads();

    bf16x8v av[4], bv[4];
#pragma unroll
    for (int i = 0; i < 4; ++i) {
      const int ra = wr + 16 * i + l15;
      av[i] = *(const bf16x8v*)&lds_a[ra * 32 + ((quad ^ ((ra >> 1) & 3)) * 8)];
    }
#pragma unroll
    for (int j = 0; j < 4; ++j) {
      const int rb = wc + 16 * j + l15;
      bv[j] = *(const bf16x8v*)&lds_b[rb * 32 + ((quad ^ ((rb >> 1) & 3)) * 8)];
    }
#pragma unroll
    for (int i = 0; i < 4; ++i)
#pragma unroll
      for (int j = 0; j < 4; ++j)
        acc[i][j] = __builtin_amdgcn_mfma_f32_16x16x32_bf16(av[i], bv[j], acc[i][j], 0, 0, 0);
  }
}

// Fused K/V/R GEMM: W_cat is 2304x768 (rows 0-767 = w_key, 768-1535 = w_value,
// 1536-2303 = w_receptance). Outputs bf16; receptance gets sigmoid.
__global__ __launch_bounds__(256) void gemm_kvr(
    const bf16* __restrict__ A, const bf16* __restrict__ Wcat,
    bf16* __restrict__ Kb, bf16* __restrict__ Vb, bf16* __restrict__ SRb)
{
  __shared__ __align__(16) bf16 lds_a[128 * 32];
  __shared__ __align__(16) bf16 lds_b[128 * 32];
  const int tid = threadIdx.x;
  const size_t m0 = (size_t)blockIdx.x * 128;
  const int n0 = blockIdx.y * 128;               // 0..2176
  f32x4v acc[4][4];
  gemm_tile_acc(A, Wcat, lds_a, lds_b, tid, m0, n0, acc);

  const int seg   = n0 / 768;                    // 0=K 1=V 2=R (tile within one seg)
  const int ncol0 = n0 - seg * 768;
  bf16* __restrict__ dst = (seg == 0) ? Kb : (seg == 1) ? Vb : SRb;
  const int lane = tid & 63, wave = tid >> 6;
  const int quad = lane >> 4, l15 = lane & 15;
  const int wr = (wave >> 1) * 64, wc = (wave & 1) * 64;
#pragma unroll
  for (int i = 0; i < 4; ++i) {
    const size_t mrow = m0 + wr + 16 * i + quad * 4;
#pragma unroll
    for (int j = 0; j < 4; ++j) {
      const int col = ncol0 + wc + 16 * j + l15;
#pragma unroll
      for (int r = 0; r < 4; ++r) {
        float val = acc[i][j][r];
        if (seg == 2) val = 1.0f / (1.0f + __expf(-val));
        dst[(mrow + r) * 768 + col] = __float2bfloat16(val);
      }
    }
  }
}

// Output GEMM: fp32 out.
__global__ __launch_bounds__(256) void gemm_out(
    const bf16* __restrict__ A, const bf16* __restrict__ W,
    float* __restrict__ out)
{
  __shared__ __align__(16) bf16 lds_a[128 * 32];
  __shared__ __align__(16) bf16 lds_b[128 * 32];
  const int tid = threadIdx.x;
  const size_t m0 = (size_t)blockIdx.x * 128;
  const int n0 = blockIdx.y * 128;
  f32x4v acc[4][4];
  gemm_tile_acc(A, W, lds_a, lds_b, tid, m0, n0, acc);

  const int lane = tid & 63, wave = tid >> 6;
  const int quad = lane >> 4, l15 = lane & 15;
  const int wr = (wave >> 1) * 64, wc = (wave & 1) * 64;
#pragma unroll
  for (int i = 0; i < 4; ++i) {
    const size_t mrow = m0 + wr + 16 * i + quad * 4;
#pragma unroll
    for (int j = 0; j < 4; ++j) {
      const int col = n0 + wc + 16 * j + l15;
#pragma unroll
      for (int r = 0; r < 4; ++r)
        out[(mrow + r) * 768 + col] = acc[i][j][r];
    }
  }
}

// ------------------------------------------------------------ WKV chunk scan
// G=64 chunks of L=64. State (aa,bb,pp). K,V now bf16; state math fp32.
__global__ void wkv_phaseA(const bf16* __restrict__ K, const bf16* __restrict__ V,
                           const float* __restrict__ sd,
                           float* __restrict__ sA, float* __restrict__ sB, float* __restrict__ sP)
{
  const int idx = blockIdx.x * 256 + threadIdx.x;   // B*G*C = 393216
  const int c  = idx % 768;
  const int bg = idx / 768;
  const int g  = bg & 63;
  const int b  = bg >> 6;
  const float w = sd[c] * (1.0f / 4096.0f);
  float aa = 0.f, bb = 0.f, pp = -1e38f;
  const size_t base = ((size_t)b * 4096 + (size_t)g * 64) * 768 + c;
#pragma unroll 4
  for (int t = 0; t < 64; ++t) {
    const float kt = __bfloat162float(K[base + (size_t)t * 768]);
    const float vt = __bfloat162float(V[base + (size_t)t * 768]);
    const float ww2 = w + pp;
    const float p2  = fmaxf(ww2, kt);
    const float e1b = __expf(ww2 - p2);
    const float e2b = __expf(kt - p2);
    aa = e1b * aa + e2b * vt;
    bb = e1b * bb + e2b;
    pp = p2;
  }
  const int o = g * 6144 + b * 768 + c;
  sA[o] = aa; sB[o] = bb; sP[o] = pp;
}

__global__ void wkv_phaseB(const float* __restrict__ sA, const float* __restrict__ sB,
                           const float* __restrict__ sP,
                           float* __restrict__ iA, float* __restrict__ iB, float* __restrict__ iP,
                           const float* __restrict__ sd)
{
  const int bc = blockIdx.x * 256 + threadIdx.x;    // B*C = 6144
  const int c  = bc % 768;
  const float Lw = 64.0f * (sd[c] * (1.0f / 4096.0f));
  float aa = 0.f, bb = 0.f, pp = -1e38f;
  for (int g = 0; g < 64; ++g) {
    const int o = g * 6144 + bc;
    iA[o] = aa; iB[o] = bb; iP[o] = pp;             // state BEFORE chunk g
    const float la = sA[o], lb = sB[o], lp = sP[o];
    const float pd = pp + Lw;
    const float pn = fmaxf(pd, lp);
    const float e0 = __expf(pd - pn);
    const float e1 = __expf(lp - pn);
    aa = e0 * aa + e1 * la;
    bb = e0 * bb + e1 * lb;
    pp = pn;
  }
}

__global__ void wkv_phaseC(const bf16* __restrict__ K, const bf16* __restrict__ V,
                           const bf16* __restrict__ SR,
                           const float* __restrict__ iA, const float* __restrict__ iB,
                           const float* __restrict__ iP,
                           const float* __restrict__ sd, const float* __restrict__ sf,
                           bf16* __restrict__ RY)
{
  const int idx = blockIdx.x * 256 + threadIdx.x;
  const int c  = idx % 768;
  const int bg = idx / 768;
  const int g  = bg & 63;
  const int b  = bg >> 6;
  const float w = sd[c] * (1.0f / 4096.0f);
  const float u = sf[c] * (1.0f / 4096.0f);
  const int o = g * 6144 + b * 768 + c;
  float aa = iA[o], bb = iB[o], pp = iP[o];
  const size_t base = ((size_t)b * 4096 + (size_t)g * 64) * 768 + c;
#pragma unroll 4
  for (int t = 0; t < 64; ++t) {
    const float kt = __bfloat162float(K[base + (size_t)t * 768]);
    const float vt = __bfloat162float(V[base + (size_t)t * 768]);
    const float ww = u + kt;
    const float p  = fmaxf(pp, ww);
    const float e1 = __expf(pp - p);
    const float e2 = __expf(ww - p);
    const float y  = (e1 * aa + e2 * vt) / (e1 * bb + e2);
    const float s  = __bfloat162float(SR[base + (size_t)t * 768]);
    RY[base + (size_t)t * 768] = __float2bfloat16(s * y);
    const float ww2 = w + pp;
    const float p2  = fmaxf(ww2, kt);
    const float e1b = __expf(ww2 - p2);
    const float e2b = __expf(kt - p2);
    aa = e1b * aa + e2b * vt;
    bb = e1b * bb + e2b;
    pp = p2;
  }
}

// ---------------------------------------------------------------------------
extern "C" void kernel_launch(void* const* d_in, const int* in_sizes, int n_in,
                              void* d_out, int out_size, void* d_ws, size_t ws_size,
                              hipStream_t stream)
{
  const float* x  = (const float*)d_in[0];
  const float* wk = (const float*)d_in[1];
  const float* wv = (const float*)d_in[2];
  const float* wr = (const float*)d_in[3];
  const float* wo = (const float*)d_in[4];
  const float* sd = (const float*)d_in[5];
  const float* sf = (const float*)d_in[6];
  float* out = (float*)d_out;

  char* ws = (char*)d_ws;
  // workspace layout (215,482,368 bytes total)
  bf16*  x_bf  = (bf16*) (ws + 0);            // 25165824 * 2
  bf16*  wcat  = (bf16*) (ws + 50331648);     // 2304x768 bf16 (k|v|r stacked)
  bf16*  wo_bf = (bf16*) (ws + 53870592);
  bf16*  Kb    = (bf16*) (ws + 55050240);     // 25165824 * 2 each
  bf16*  Vb    = (bf16*) (ws + 105381888);
  bf16*  SRb   = (bf16*) (ws + 155713536);
  float* sumA  = (float*)(ws + 206045184);    // 64*6144 * 4 each
  float* sumB  = (float*)(ws + 207618048);
  float* sumP  = (float*)(ws + 209190912);
  float* iniA  = (float*)(ws + 210763776);
  float* iniB  = (float*)(ws + 212336640);
  float* iniP  = (float*)(ws + 213909504);
  bf16*  ry_bf = x_bf;                        // x dead after gemm_kvr -> alias

  f2b4<<<24576, 256, 0, stream>>>(x,  x_bf,  6291456);
  f2b4<<<576,   256, 0, stream>>>(wk, wcat,            147456);
  f2b4<<<576,   256, 0, stream>>>(wv, wcat + 589824,   147456);
  f2b4<<<576,   256, 0, stream>>>(wr, wcat + 1179648,  147456);
  f2b4<<<576,   256, 0, stream>>>(wo, wo_bf,           147456);

  dim3 gkvr(256, 18);
  gemm_kvr<<<gkvr, 256, 0, stream>>>(x_bf, wcat, Kb, Vb, SRb);

  wkv_phaseA<<<1536, 256, 0, stream>>>(Kb, Vb, sd, sumA, sumB, sumP);
  wkv_phaseB<<<24,   256, 0, stream>>>(sumA, sumB, sumP, iniA, iniB, iniP, sd);
  wkv_phaseC<<<1536, 256, 0, stream>>>(Kb, Vb, SRb, iniA, iniB, iniP, sd, sf, ry_bf);

  dim3 gout(256, 6);
  gemm_out<<<gout, 256, 0, stream>>>(ry_bf, wo_bf, out);
}

// Round 3
// 484.904 us; speedup vs baseline: 1.2022x; 1.0333x over previous
//
#include <hip/hip_runtime.h>
#include <hip/hip_bf16.h>

using bf16 = __hip_bfloat16;
typedef short bf16x8v __attribute__((ext_vector_type(8)));
typedef float f32x4v  __attribute__((ext_vector_type(4)));

#define GLD_LDS16(g, l) __builtin_amdgcn_global_load_lds(                      \
    (const __attribute__((address_space(1))) void*)(g),                        \
    (__attribute__((address_space(3))) void*)(l), 16, 0, 0)

__device__ __forceinline__ float bflo(unsigned int u) {
  union { unsigned int i; float f; } c; c.i = u << 16; return c.f;
}
__device__ __forceinline__ float bfhi(unsigned int u) {
  union { unsigned int i; float f; } c; c.i = u & 0xffff0000u; return c.f;
}
__device__ __forceinline__ unsigned int packbf(float a, float b) {
  return (unsigned int)(__hip_bfloat16_raw(__float2bfloat16(a)).x) |
         ((unsigned int)(__hip_bfloat16_raw(__float2bfloat16(b)).x) << 16);
}

// ---------------------------------------------------------------- fp32->bf16
__global__ void f2b4(const float* __restrict__ s, bf16* __restrict__ d, int n4) {
  int i = blockIdx.x * blockDim.x + threadIdx.x;
  if (i >= n4) return;
  const float4 f = reinterpret_cast<const float4*>(s)[i];
  struct B4 { bf16 a, b, c, d; };
  B4 o = { __float2bfloat16(f.x), __float2bfloat16(f.y),
           __float2bfloat16(f.z), __float2bfloat16(f.w) };
  reinterpret_cast<B4*>(d)[i] = o;
}

// --------------------------------------------------------------- GEMM core
// 128x128 tile, BK=64 (12 K-iters, half the barrier drains of BK=32).
// LDS: row stride 64 elems = 128 B = one full bank period; 16B-granule g of
// row r stored with global k-offset granule g^(r&7) -> fragment ds_read_b128
// spreads 2-way per granule (free, m136); staging slot = tid*16B (contiguous,
// global_load_lds-compatible: swizzle permutes SOURCE addresses, not dests).
__device__ __forceinline__ void gemm_tile_acc(
    const bf16* __restrict__ A, const bf16* __restrict__ W,
    bf16* lds_a, bf16* lds_b, int tid, size_t m0, int n0, f32x4v acc[4][4])
{
  const int lane = tid & 63;
  const int wave = tid >> 6;
  const int quad = lane >> 4;
  const int l15  = lane & 15;
  const int wr   = (wave >> 1) * 64;
  const int wc   = (wave & 1) * 64;

  int srow[4], scol[4];
#pragma unroll
  for (int q = 0; q < 4; ++q) {
    const int s = tid + q * 256;
    srow[q] = s >> 3;
    scol[q] = (((s & 7) ^ (srow[q] & 7)) * 8);
  }

#pragma unroll
  for (int i = 0; i < 4; ++i)
#pragma unroll
    for (int j = 0; j < 4; ++j)
#pragma unroll
      for (int r = 0; r < 4; ++r) acc[i][j][r] = 0.0f;

  for (int k0 = 0; k0 < 768; k0 += 64) {
    __syncthreads();
#pragma unroll
    for (int q = 0; q < 4; ++q)
      GLD_LDS16(A + (m0 + srow[q]) * 768 + k0 + scol[q], &lds_a[(size_t)(tid + q * 256) * 8]);
#pragma unroll
    for (int q = 0; q < 4; ++q)
      GLD_LDS16(W + (size_t)(n0 + srow[q]) * 768 + k0 + scol[q], &lds_b[(size_t)(tid + q * 256) * 8]);
    __syncthreads();

#pragma unroll
    for (int h = 0; h < 2; ++h) {
      bf16x8v av[4], bv[4];
#pragma unroll
      for (int i = 0; i < 4; ++i) {
        const int ra = wr + 16 * i + l15;
        const int gl = h * 4 + quad;
        av[i] = *(const bf16x8v*)&lds_a[ra * 64 + ((gl ^ (ra & 7)) * 8)];
      }
#pragma unroll
      for (int j = 0; j < 4; ++j) {
        const int rb = wc + 16 * j + l15;
        const int gl = h * 4 + quad;
        bv[j] = *(const bf16x8v*)&lds_b[rb * 64 + ((gl ^ (rb & 7)) * 8)];
      }
#pragma unroll
      for (int i = 0; i < 4; ++i)
#pragma unroll
        for (int j = 0; j < 4; ++j)
          acc[i][j] = __builtin_amdgcn_mfma_f32_16x16x32_bf16(av[i], bv[j], acc[i][j], 0, 0, 0);
    }
  }
}

// Fused K/V/R GEMM. Linear grid 4608 decoded as: chunk(4) x ntile(18) x mm(64),
// mm fastest (64 consecutive blocks share one W tile; chunk's A slice = 12 MB
// = 1.5 MB/XCD stays L2-resident across all 18 n-passes).
__global__ __launch_bounds__(256) void gemm_kvr(
    const bf16* __restrict__ A, const bf16* __restrict__ Wcat,
    bf16* __restrict__ Kb, bf16* __restrict__ Vb, bf16* __restrict__ SRb)
{
  __shared__ __align__(16) bf16 lds_a[128 * 64];
  __shared__ __align__(16) bf16 lds_b[128 * 64];
  const int tid = threadIdx.x;
  const int bx = blockIdx.x;
  const int chunk = bx / 1152;
  const int rem   = bx % 1152;
  const int mm    = rem & 63;
  const int nt    = rem >> 6;                    // 0..17
  const size_t m0 = (size_t)(chunk * 64 + mm) * 128;
  const int n0 = nt * 128;

  f32x4v acc[4][4];
  gemm_tile_acc(A, Wcat, lds_a, lds_b, tid, m0, n0, acc);

  const int seg   = n0 / 768;                    // 0=K 1=V 2=R
  const int ncol0 = n0 - seg * 768;
  bf16* __restrict__ dst = (seg == 0) ? Kb : (seg == 1) ? Vb : SRb;
  const int lane = tid & 63, wave = tid >> 6;
  const int quad = lane >> 4, l15 = lane & 15;
  const int wr = (wave >> 1) * 64, wc = (wave & 1) * 64;
#pragma unroll
  for (int i = 0; i < 4; ++i) {
    const size_t mrow = m0 + wr + 16 * i + quad * 4;
#pragma unroll
    for (int j = 0; j < 4; ++j) {
      const int col = ncol0 + wc + 16 * j + l15;
#pragma unroll
      for (int r = 0; r < 4; ++r) {
        float val = acc[i][j][r];
        if (seg == 2) val = 1.0f / (1.0f + __expf(-val));
        dst[(mrow + r) * 768 + col] = __float2bfloat16(val);
      }
    }
  }
}

// Output GEMM: fp32 out. Linear grid 1536 = chunk(4) x ntile(6) x mm(64).
__global__ __launch_bounds__(256) void gemm_out(
    const bf16* __restrict__ A, const bf16* __restrict__ W,
    float* __restrict__ out)
{
  __shared__ __align__(16) bf16 lds_a[128 * 64];
  __shared__ __align__(16) bf16 lds_b[128 * 64];
  const int tid = threadIdx.x;
  const int bx = blockIdx.x;
  const int chunk = bx / 384;
  const int rem   = bx % 384;
  const int mm    = rem & 63;
  const int nt    = rem >> 6;                    // 0..5
  const size_t m0 = (size_t)(chunk * 64 + mm) * 128;
  const int n0 = nt * 128;

  f32x4v acc[4][4];
  gemm_tile_acc(A, W, lds_a, lds_b, tid, m0, n0, acc);

  const int lane = tid & 63, wave = tid >> 6;
  const int quad = lane >> 4, l15 = lane & 15;
  const int wr = (wave >> 1) * 64, wc = (wave & 1) * 64;
#pragma unroll
  for (int i = 0; i < 4; ++i) {
    const size_t mrow = m0 + wr + 16 * i + quad * 4;
#pragma unroll
    for (int j = 0; j < 4; ++j) {
      const int col = n0 + wc + 16 * j + l15;
#pragma unroll
      for (int r = 0; r < 4; ++r)
        out[(mrow + r) * 768 + col] = acc[i][j][r];
    }
  }
}

// ------------------------------------------------------------ WKV chunk scan
// G=64 chunks of L=64. Each thread now carries TWO channels (packed bf16x2
// loads, two independent exp chains for ILP). State math fp32.
__global__ void wkv_phaseA(const bf16* __restrict__ K, const bf16* __restrict__ V,
                           const float* __restrict__ sd,
                           float* __restrict__ sA, float* __restrict__ sB, float* __restrict__ sP)
{
  const int idx = blockIdx.x * 256 + threadIdx.x;   // B*G*C/2 = 196608
  const int c2 = idx % 384;
  const int bg = idx / 384;
  const int g  = bg & 63;
  const int b  = bg >> 6;
  const int c0 = c2 * 2;
  const float w0 = sd[c0] * (1.0f / 4096.0f);
  const float w1 = sd[c0 + 1] * (1.0f / 4096.0f);
  float aa0 = 0.f, bb0 = 0.f, pp0 = -1e38f;
  float aa1 = 0.f, bb1 = 0.f, pp1 = -1e38f;
  const size_t base = ((size_t)b * 4096 + (size_t)g * 64) * 768 + c0;
  const unsigned int* Kp = (const unsigned int*)(K + base);
  const unsigned int* Vp = (const unsigned int*)(V + base);
#pragma unroll 8
  for (int t = 0; t < 64; ++t) {
    const unsigned int ku = Kp[(size_t)t * 384];
    const unsigned int vu = Vp[(size_t)t * 384];
    { const float kt = bflo(ku), vt = bflo(vu);
      const float ww2 = w0 + pp0;
      const float p2  = fmaxf(ww2, kt);
      const float e1b = __expf(ww2 - p2);
      const float e2b = __expf(kt - p2);
      aa0 = e1b * aa0 + e2b * vt; bb0 = e1b * bb0 + e2b; pp0 = p2; }
    { const float kt = bfhi(ku), vt = bfhi(vu);
      const float ww2 = w1 + pp1;
      const float p2  = fmaxf(ww2, kt);
      const float e1b = __expf(ww2 - p2);
      const float e2b = __expf(kt - p2);
      aa1 = e1b * aa1 + e2b * vt; bb1 = e1b * bb1 + e2b; pp1 = p2; }
  }
  const int o = g * 6144 + b * 768 + c0;
  sA[o] = aa0; sB[o] = bb0; sP[o] = pp0;
  sA[o + 1] = aa1; sB[o + 1] = bb1; sP[o + 1] = pp1;
}

__global__ void wkv_phaseB(const float* __restrict__ sA, const float* __restrict__ sB,
                           const float* __restrict__ sP,
                           float* __restrict__ iA, float* __restrict__ iB, float* __restrict__ iP,
                           const float* __restrict__ sd)
{
  const int bc = blockIdx.x * 256 + threadIdx.x;    // B*C = 6144
  const int c  = bc % 768;
  const float Lw = 64.0f * (sd[c] * (1.0f / 4096.0f));
  float aa = 0.f, bb = 0.f, pp = -1e38f;
  for (int g = 0; g < 64; ++g) {
    const int o = g * 6144 + bc;
    iA[o] = aa; iB[o] = bb; iP[o] = pp;             // state BEFORE chunk g
    const float la = sA[o], lb = sB[o], lp = sP[o];
    const float pd = pp + Lw;
    const float pn = fmaxf(pd, lp);
    const float e0 = __expf(pd - pn);
    const float e1 = __expf(lp - pn);
    aa = e0 * aa + e1 * la;
    bb = e0 * bb + e1 * lb;
    pp = pn;
  }
}

__global__ void wkv_phaseC(const bf16* __restrict__ K, const bf16* __restrict__ V,
                           const bf16* __restrict__ SR,
                           const float* __restrict__ iA, const float* __restrict__ iB,
                           const float* __restrict__ iP,
                           const float* __restrict__ sd, const float* __restrict__ sf,
                           bf16* __restrict__ RY)
{
  const int idx = blockIdx.x * 256 + threadIdx.x;   // 196608
  const int c2 = idx % 384;
  const int bg = idx / 384;
  const int g  = bg & 63;
  const int b  = bg >> 6;
  const int c0 = c2 * 2;
  const float w0 = sd[c0] * (1.0f / 4096.0f);
  const float w1 = sd[c0 + 1] * (1.0f / 4096.0f);
  const float u0 = sf[c0] * (1.0f / 4096.0f);
  const float u1 = sf[c0 + 1] * (1.0f / 4096.0f);
  const int o = g * 6144 + b * 768 + c0;
  float aa0 = iA[o], bb0 = iB[o], pp0 = iP[o];
  float aa1 = iA[o + 1], bb1 = iB[o + 1], pp1 = iP[o + 1];
  const size_t base = ((size_t)b * 4096 + (size_t)g * 64) * 768 + c0;
  const unsigned int* Kp = (const unsigned int*)(K + base);
  const unsigned int* Vp = (const unsigned int*)(V + base);
  const unsigned int* Sp = (const unsigned int*)(SR + base);
  unsigned int* Rp = (unsigned int*)(RY + base);
#pragma unroll 8
  for (int t = 0; t < 64; ++t) {
    const unsigned int ku = Kp[(size_t)t * 384];
    const unsigned int vu = Vp[(size_t)t * 384];
    const unsigned int su = Sp[(size_t)t * 384];
    float y0, y1;
    { const float kt = bflo(ku), vt = bflo(vu);
      const float ww = u0 + kt;
      const float p  = fmaxf(pp0, ww);
      const float e1 = __expf(pp0 - p);
      const float e2 = __expf(ww - p);
      y0 = (e1 * aa0 + e2 * vt) / (e1 * bb0 + e2) * bflo(su);
      const float ww2 = w0 + pp0;
      const float p2  = fmaxf(ww2, kt);
      const float e1b = __expf(ww2 - p2);
      const float e2b = __expf(kt - p2);
      aa0 = e1b * aa0 + e2b * vt; bb0 = e1b * bb0 + e2b; pp0 = p2; }
    { const float kt = bfhi(ku), vt = bfhi(vu);
      const float ww = u1 + kt;
      const float p  = fmaxf(pp1, ww);
      const float e1 = __expf(pp1 - p);
      const float e2 = __expf(ww - p);
      y1 = (e1 * aa1 + e2 * vt) / (e1 * bb1 + e2) * bfhi(su);
      const float ww2 = w1 + pp1;
      const float p2  = fmaxf(ww2, kt);
      const float e1b = __expf(ww2 - p2);
      const float e2b = __expf(kt - p2);
      aa1 = e1b * aa1 + e2b * vt; bb1 = e1b * bb1 + e2b; pp1 = p2; }
    Rp[(size_t)t * 384] = packbf(y0, y1);
  }
}

// ---------------------------------------------------------------------------
extern "C" void kernel_launch(void* const* d_in, const int* in_sizes, int n_in,
                              void* d_out, int out_size, void* d_ws, size_t ws_size,
                              hipStream_t stream)
{
  const float* x  = (const float*)d_in[0];
  const float* wk = (const float*)d_in[1];
  const float* wv = (const float*)d_in[2];
  const float* wr = (const float*)d_in[3];
  const float* wo = (const float*)d_in[4];
  const float* sd = (const float*)d_in[5];
  const float* sf = (const float*)d_in[6];
  float* out = (float*)d_out;

  char* ws = (char*)d_ws;
  bf16*  x_bf  = (bf16*) (ws + 0);            // 25165824 * 2
  bf16*  wcat  = (bf16*) (ws + 50331648);     // 2304x768 bf16 (k|v|r stacked)
  bf16*  wo_bf = (bf16*) (ws + 53870592);
  bf16*  Kb    = (bf16*) (ws + 55050240);     // 25165824 * 2 each
  bf16*  Vb    = (bf16*) (ws + 105381888);
  bf16*  SRb   = (bf16*) (ws + 155713536);
  float* sumA  = (float*)(ws + 206045184);    // 64*6144 * 4 each
  float* sumB  = (float*)(ws + 207618048);
  float* sumP  = (float*)(ws + 209190912);
  float* iniA  = (float*)(ws + 210763776);
  float* iniB  = (float*)(ws + 212336640);
  float* iniP  = (float*)(ws + 213909504);
  bf16*  ry_bf = x_bf;                        // x dead after gemm_kvr -> alias

  f2b4<<<24576, 256, 0, stream>>>(x,  x_bf,  6291456);
  f2b4<<<576,   256, 0, stream>>>(wk, wcat,            147456);
  f2b4<<<576,   256, 0, stream>>>(wv, wcat + 589824,   147456);
  f2b4<<<576,   256, 0, stream>>>(wr, wcat + 1179648,  147456);
  f2b4<<<576,   256, 0, stream>>>(wo, wo_bf,           147456);

  gemm_kvr<<<4608, 256, 0, stream>>>(x_bf, wcat, Kb, Vb, SRb);

  wkv_phaseA<<<768, 256, 0, stream>>>(Kb, Vb, sd, sumA, sumB, sumP);
  wkv_phaseB<<<24,  256, 0, stream>>>(sumA, sumB, sumP, iniA, iniB, iniP, sd);
  wkv_phaseC<<<768, 256, 0, stream>>>(Kb, Vb, SRb, iniA, iniB, iniP, sd, sf, ry_bf);

  gemm_out<<<1536, 256, 0, stream>>>(ry_bf, wo_bf, out);
}

// Round 4
// 472.167 us; speedup vs baseline: 1.2346x; 1.0270x over previous
//
#include <hip/hip_runtime.h>
#include <hip/hip_bf16.h>

using bf16 = __hip_bfloat16;
typedef short bf16x8v __attribute__((ext_vector_type(8)));
typedef float f32x4v  __attribute__((ext_vector_type(4)));

#define GLD_LDS16(g, l) __builtin_amdgcn_global_load_lds(                      \
    (const __attribute__((address_space(1))) void*)(g),                        \
    (__attribute__((address_space(3))) void*)(l), 16, 0, 0)

__device__ __forceinline__ float bflo(unsigned int u) {
  union { unsigned int i; float f; } c; c.i = u << 16; return c.f;
}
__device__ __forceinline__ float bfhi(unsigned int u) {
  union { unsigned int i; float f; } c; c.i = u & 0xffff0000u; return c.f;
}
__device__ __forceinline__ unsigned int packbf(float a, float b) {
  return (unsigned int)(__hip_bfloat16_raw(__float2bfloat16(a)).x) |
         ((unsigned int)(__hip_bfloat16_raw(__float2bfloat16(b)).x) << 16);
}

// ------------------------------------------------- all fp32->bf16 casts, one launch
// region 0: x (6291456 float4s) -> x_bf
// regions 1-3: wk/wv/wr (147456 float4s each) -> wcat at seg*589824 elems
// region 4: wo -> wo_bf
__global__ void f2b4_all(const float* __restrict__ x,  const float* __restrict__ wk,
                         const float* __restrict__ wv, const float* __restrict__ wr,
                         const float* __restrict__ wo,
                         bf16* __restrict__ x_bf, bf16* __restrict__ wcat,
                         bf16* __restrict__ wo_bf) {
  int i = blockIdx.x * blockDim.x + threadIdx.x;
  const float* s; bf16* d; int idx;
  if (i < 6291456) { s = x; d = x_bf; idx = i; }
  else {
    int j = i - 6291456;
    int seg = j / 147456;
    idx = j - seg * 147456;
    if (seg == 0)      { s = wk; d = wcat; }
    else if (seg == 1) { s = wv; d = wcat + 589824; }
    else if (seg == 2) { s = wr; d = wcat + 1179648; }
    else               { s = wo; d = wo_bf; }
  }
  const float4 f = reinterpret_cast<const float4*>(s)[idx];
  struct B4 { bf16 a, b, c, d; };
  B4 o = { __float2bfloat16(f.x), __float2bfloat16(f.y),
           __float2bfloat16(f.z), __float2bfloat16(f.w) };
  reinterpret_cast<B4*>(d)[idx] = o;
}

// --------------------------------------------------------------- GEMM core
// 128x128 tile, BK=64. LDS XOR swizzle (granule g^(r&7)) -> 0 bank conflicts
// (verified R2/R3). Staging slot = tid*16B (global_load_lds-compatible).
__device__ __forceinline__ void gemm_tile_acc(
    const bf16* __restrict__ A, const bf16* __restrict__ W,
    bf16* lds_a, bf16* lds_b, int tid, size_t m0, int n0, f32x4v acc[4][4])
{
  const int lane = tid & 63;
  const int wave = tid >> 6;
  const int quad = lane >> 4;
  const int l15  = lane & 15;
  const int wr   = (wave >> 1) * 64;
  const int wc   = (wave & 1) * 64;

  int srow[4], scol[4];
#pragma unroll
  for (int q = 0; q < 4; ++q) {
    const int s = tid + q * 256;
    srow[q] = s >> 3;
    scol[q] = (((s & 7) ^ (srow[q] & 7)) * 8);
  }

#pragma unroll
  for (int i = 0; i < 4; ++i)
#pragma unroll
    for (int j = 0; j < 4; ++j)
#pragma unroll
      for (int r = 0; r < 4; ++r) acc[i][j][r] = 0.0f;

  for (int k0 = 0; k0 < 768; k0 += 64) {
    __syncthreads();
#pragma unroll
    for (int q = 0; q < 4; ++q)
      GLD_LDS16(A + (m0 + srow[q]) * 768 + k0 + scol[q], &lds_a[(size_t)(tid + q * 256) * 8]);
#pragma unroll
    for (int q = 0; q < 4; ++q)
      GLD_LDS16(W + (size_t)(n0 + srow[q]) * 768 + k0 + scol[q], &lds_b[(size_t)(tid + q * 256) * 8]);
    __syncthreads();

#pragma unroll
    for (int h = 0; h < 2; ++h) {
      bf16x8v av[4], bv[4];
#pragma unroll
      for (int i = 0; i < 4; ++i) {
        const int ra = wr + 16 * i + l15;
        const int gl = h * 4 + quad;
        av[i] = *(const bf16x8v*)&lds_a[ra * 64 + ((gl ^ (ra & 7)) * 8)];
      }
#pragma unroll
      for (int j = 0; j < 4; ++j) {
        const int rb = wc + 16 * j + l15;
        const int gl = h * 4 + quad;
        bv[j] = *(const bf16x8v*)&lds_b[rb * 64 + ((gl ^ (rb & 7)) * 8)];
      }
#pragma unroll
      for (int i = 0; i < 4; ++i)
#pragma unroll
        for (int j = 0; j < 4; ++j)
          acc[i][j] = __builtin_amdgcn_mfma_f32_16x16x32_bf16(av[i], bv[j], acc[i][j], 0, 0, 0);
    }
  }
}

// Fused K/V/R GEMM. grid 4608 = chunk(4) x ntile(18) x mm(64), mm fastest.
__global__ __launch_bounds__(256) void gemm_kvr(
    const bf16* __restrict__ A, const bf16* __restrict__ Wcat,
    bf16* __restrict__ Kb, bf16* __restrict__ Vb, bf16* __restrict__ SRb)
{
  __shared__ __align__(16) bf16 lds_a[128 * 64];
  __shared__ __align__(16) bf16 lds_b[128 * 64];
  const int tid = threadIdx.x;
  const int bx = blockIdx.x;
  const int chunk = bx / 1152;
  const int rem   = bx % 1152;
  const int mm    = rem & 63;
  const int nt    = rem >> 6;
  const size_t m0 = (size_t)(chunk * 64 + mm) * 128;
  const int n0 = nt * 128;

  f32x4v acc[4][4];
  gemm_tile_acc(A, Wcat, lds_a, lds_b, tid, m0, n0, acc);

  const int seg   = n0 / 768;
  const int ncol0 = n0 - seg * 768;
  bf16* __restrict__ dst = (seg == 0) ? Kb : (seg == 1) ? Vb : SRb;
  const int lane = tid & 63, wave = tid >> 6;
  const int quad = lane >> 4, l15 = lane & 15;
  const int wr = (wave >> 1) * 64, wc = (wave & 1) * 64;
#pragma unroll
  for (int i = 0; i < 4; ++i) {
    const size_t mrow = m0 + wr + 16 * i + quad * 4;
#pragma unroll
    for (int j = 0; j < 4; ++j) {
      const int col = ncol0 + wc + 16 * j + l15;
#pragma unroll
      for (int r = 0; r < 4; ++r) {
        float val = acc[i][j][r];
        if (seg == 2) val = 1.0f / (1.0f + __expf(-val));
        dst[(mrow + r) * 768 + col] = __float2bfloat16(val);
      }
    }
  }
}

// Output GEMM: fp32 out. grid 1536 = chunk(4) x ntile(6) x mm(64).
__global__ __launch_bounds__(256) void gemm_out(
    const bf16* __restrict__ A, const bf16* __restrict__ W,
    float* __restrict__ out)
{
  __shared__ __align__(16) bf16 lds_a[128 * 64];
  __shared__ __align__(16) bf16 lds_b[128 * 64];
  const int tid = threadIdx.x;
  const int bx = blockIdx.x;
  const int chunk = bx / 384;
  const int rem   = bx % 384;
  const int mm    = rem & 63;
  const int nt    = rem >> 6;
  const size_t m0 = (size_t)(chunk * 64 + mm) * 128;
  const int n0 = nt * 128;

  f32x4v acc[4][4];
  gemm_tile_acc(A, W, lds_a, lds_b, tid, m0, n0, acc);

  const int lane = tid & 63, wave = tid >> 6;
  const int quad = lane >> 4, l15 = lane & 15;
  const int wr = (wave >> 1) * 64, wc = (wave & 1) * 64;
#pragma unroll
  for (int i = 0; i < 4; ++i) {
    const size_t mrow = m0 + wr + 16 * i + quad * 4;
#pragma unroll
    for (int j = 0; j < 4; ++j) {
      const int col = n0 + wc + 16 * j + l15;
#pragma unroll
      for (int r = 0; r < 4; ++r)
        out[(mrow + r) * 768 + col] = acc[i][j][r];
    }
  }
}

// ------------------------------------------------------------ WKV chunk scan
// G=128 chunks of L=32. 4 channels/thread (uint2 = 4xbf16 loads, 4 independent
// exp chains). State math fp32. Threads = B*G*C/4 = 196608.
__global__ void wkv_phaseA(const bf16* __restrict__ K, const bf16* __restrict__ V,
                           const float* __restrict__ sd,
                           float* __restrict__ sA, float* __restrict__ sB, float* __restrict__ sP)
{
  const int idx = blockIdx.x * 256 + threadIdx.x;
  const int c4 = idx % 192;
  const int bg = idx / 192;
  const int g  = bg & 127;
  const int b  = bg >> 7;
  const int c0 = c4 * 4;
  float w[4], aa[4], bb[4], pp[4];
#pragma unroll
  for (int e = 0; e < 4; ++e) {
    w[e] = sd[c0 + e] * (1.0f / 4096.0f);
    aa[e] = 0.f; bb[e] = 0.f; pp[e] = -1e38f;
  }
  const size_t base = ((size_t)b * 4096 + (size_t)g * 32) * 768 + c0;
  const uint2* Kp = (const uint2*)(K + base);
  const uint2* Vp = (const uint2*)(V + base);
#pragma unroll 4
  for (int t = 0; t < 32; ++t) {
    const uint2 ku = Kp[(size_t)t * 192];
    const uint2 vu = Vp[(size_t)t * 192];
    const float kc[4] = { bflo(ku.x), bfhi(ku.x), bflo(ku.y), bfhi(ku.y) };
    const float vc[4] = { bflo(vu.x), bfhi(vu.x), bflo(vu.y), bfhi(vu.y) };
#pragma unroll
    for (int e = 0; e < 4; ++e) {
      const float ww2 = w[e] + pp[e];
      const float p2  = fmaxf(ww2, kc[e]);
      const float e1b = __expf(ww2 - p2);
      const float e2b = __expf(kc[e] - p2);
      aa[e] = e1b * aa[e] + e2b * vc[e];
      bb[e] = e1b * bb[e] + e2b;
      pp[e] = p2;
    }
  }
  const int o = g * 6144 + b * 768 + c0;
#pragma unroll
  for (int e = 0; e < 4; ++e) { sA[o + e] = aa[e]; sB[o + e] = bb[e]; sP[o + e] = pp[e]; }
}

__global__ void wkv_phaseB(const float* __restrict__ sA, const float* __restrict__ sB,
                           const float* __restrict__ sP,
                           float* __restrict__ iA, float* __restrict__ iB, float* __restrict__ iP,
                           const float* __restrict__ sd)
{
  const int bc = blockIdx.x * 256 + threadIdx.x;    // B*C = 6144
  const int c  = bc % 768;
  const float Lw = 32.0f * (sd[c] * (1.0f / 4096.0f));
  float aa = 0.f, bb = 0.f, pp = -1e38f;
  for (int g = 0; g < 128; ++g) {
    const int o = g * 6144 + bc;
    iA[o] = aa; iB[o] = bb; iP[o] = pp;             // state BEFORE chunk g
    const float la = sA[o], lb = sB[o], lp = sP[o];
    const float pd = pp + Lw;
    const float pn = fmaxf(pd, lp);
    const float e0 = __expf(pd - pn);
    const float e1 = __expf(lp - pn);
    aa = e0 * aa + e1 * la;
    bb = e0 * bb + e1 * lb;
    pp = pn;
  }
}

__global__ void wkv_phaseC(const bf16* __restrict__ K, const bf16* __restrict__ V,
                           const bf16* __restrict__ SR,
                           const float* __restrict__ iA, const float* __restrict__ iB,
                           const float* __restrict__ iP,
                           const float* __restrict__ sd, const float* __restrict__ sf,
                           bf16* __restrict__ RY)
{
  const int idx = blockIdx.x * 256 + threadIdx.x;
  const int c4 = idx % 192;
  const int bg = idx / 192;
  const int g  = bg & 127;
  const int b  = bg >> 7;
  const int c0 = c4 * 4;
  const int o = g * 6144 + b * 768 + c0;
  float w[4], u[4], aa[4], bb[4], pp[4];
#pragma unroll
  for (int e = 0; e < 4; ++e) {
    w[e] = sd[c0 + e] * (1.0f / 4096.0f);
    u[e] = sf[c0 + e] * (1.0f / 4096.0f);
    aa[e] = iA[o + e]; bb[e] = iB[o + e]; pp[e] = iP[o + e];
  }
  const size_t base = ((size_t)b * 4096 + (size_t)g * 32) * 768 + c0;
  const uint2* Kp = (const uint2*)(K + base);
  const uint2* Vp = (const uint2*)(V + base);
  const uint2* Sp = (const uint2*)(SR + base);
  uint2* Rp = (uint2*)(RY + base);
#pragma unroll 4
  for (int t = 0; t < 32; ++t) {
    const uint2 ku = Kp[(size_t)t * 192];
    const uint2 vu = Vp[(size_t)t * 192];
    const uint2 su = Sp[(size_t)t * 192];
    const float kc[4] = { bflo(ku.x), bfhi(ku.x), bflo(ku.y), bfhi(ku.y) };
    const float vc[4] = { bflo(vu.x), bfhi(vu.x), bflo(vu.y), bfhi(vu.y) };
    const float sc[4] = { bflo(su.x), bfhi(su.x), bflo(su.y), bfhi(su.y) };
    float y[4];
#pragma unroll
    for (int e = 0; e < 4; ++e) {
      const float ww = u[e] + kc[e];
      const float p  = fmaxf(pp[e], ww);
      const float e1 = __expf(pp[e] - p);
      const float e2 = __expf(ww - p);
      y[e] = (e1 * aa[e] + e2 * vc[e]) / (e1 * bb[e] + e2) * sc[e];
      const float ww2 = w[e] + pp[e];
      const float p2  = fmaxf(ww2, kc[e]);
      const float e1b = __expf(ww2 - p2);
      const float e2b = __expf(kc[e] - p2);
      aa[e] = e1b * aa[e] + e2b * vc[e];
      bb[e] = e1b * bb[e] + e2b;
      pp[e] = p2;
    }
    uint2 r; r.x = packbf(y[0], y[1]); r.y = packbf(y[2], y[3]);
    Rp[(size_t)t * 192] = r;
  }
}

// ---------------------------------------------------------------------------
extern "C" void kernel_launch(void* const* d_in, const int* in_sizes, int n_in,
                              void* d_out, int out_size, void* d_ws, size_t ws_size,
                              hipStream_t stream)
{
  const float* x  = (const float*)d_in[0];
  const float* wk = (const float*)d_in[1];
  const float* wv = (const float*)d_in[2];
  const float* wr = (const float*)d_in[3];
  const float* wo = (const float*)d_in[4];
  const float* sd = (const float*)d_in[5];
  const float* sf = (const float*)d_in[6];
  float* out = (float*)d_out;

  char* ws = (char*)d_ws;
  bf16*  x_bf  = (bf16*) (ws + 0);            // 25165824 * 2
  bf16*  wcat  = (bf16*) (ws + 50331648);     // 2304x768 bf16
  bf16*  wo_bf = (bf16*) (ws + 53870592);
  bf16*  Kb    = (bf16*) (ws + 55050240);     // 25165824 * 2 each
  bf16*  Vb    = (bf16*) (ws + 105381888);
  bf16*  SRb   = (bf16*) (ws + 155713536);
  float* sumA  = (float*)(ws + 206045184);    // 128*6144 floats (3 MB) each
  float* sumB  = (float*)(ws + 209190912);
  float* sumP  = (float*)(ws + 212336640);
  float* iniA  = (float*)(ws + 215482368);
  float* iniB  = (float*)(ws + 218628096);
  float* iniP  = (float*)(ws + 221773824);
  bf16*  ry_bf = x_bf;                        // x dead after gemm_kvr -> alias

  f2b4_all<<<26880, 256, 0, stream>>>(x, wk, wv, wr, wo, x_bf, wcat, wo_bf);

  gemm_kvr<<<4608, 256, 0, stream>>>(x_bf, wcat, Kb, Vb, SRb);

  wkv_phaseA<<<768, 256, 0, stream>>>(Kb, Vb, sd, sumA, sumB, sumP);
  wkv_phaseB<<<24,  256, 0, stream>>>(sumA, sumB, sumP, iniA, iniB, iniP, sd);
  wkv_phaseC<<<768, 256, 0, stream>>>(Kb, Vb, SRb, iniA, iniB, iniP, sd, sf, ry_bf);

  gemm_out<<<1536, 256, 0, stream>>>(ry_bf, wo_bf, out);
}

// Round 5
// 448.426 us; speedup vs baseline: 1.3000x; 1.0529x over previous
//
#include <hip/hip_runtime.h>
#include <hip/hip_bf16.h>

using bf16 = __hip_bfloat16;
typedef short bf16x8v  __attribute__((ext_vector_type(8)));
typedef float f32x16v  __attribute__((ext_vector_type(16)));

#define GLD_LDS16(g, l) __builtin_amdgcn_global_load_lds(                      \
    (const __attribute__((address_space(1))) void*)(g),                        \
    (__attribute__((address_space(3))) void*)(l), 16, 0, 0)

__device__ __forceinline__ float bflo(unsigned int u) {
  union { unsigned int i; float f; } c; c.i = u << 16; return c.f;
}
__device__ __forceinline__ float bfhi(unsigned int u) {
  union { unsigned int i; float f; } c; c.i = u & 0xffff0000u; return c.f;
}
__device__ __forceinline__ unsigned int packbf(float a, float b) {
  return (unsigned int)(__hip_bfloat16_raw(__float2bfloat16(a)).x) |
         ((unsigned int)(__hip_bfloat16_raw(__float2bfloat16(b)).x) << 16);
}
__device__ __forceinline__ unsigned short bfraw(float a) {
  return __hip_bfloat16_raw(__float2bfloat16(a)).x;
}

// ------------------------------------------------- all fp32->bf16 casts, one launch
__global__ void f2b4_all(const float* __restrict__ x,  const float* __restrict__ wk,
                         const float* __restrict__ wv, const float* __restrict__ wr,
                         const float* __restrict__ wo,
                         bf16* __restrict__ x_bf, bf16* __restrict__ wcat,
                         bf16* __restrict__ wo_bf) {
  int i = blockIdx.x * blockDim.x + threadIdx.x;
  const float* s; bf16* d; int idx;
  if (i < 6291456) { s = x; d = x_bf; idx = i; }
  else {
    int j = i - 6291456;
    int seg = j / 147456;
    idx = j - seg * 147456;
    if (seg == 0)      { s = wk; d = wcat; }
    else if (seg == 1) { s = wv; d = wcat + 589824; }
    else if (seg == 2) { s = wr; d = wcat + 1179648; }
    else               { s = wo; d = wo_bf; }
  }
  const float4 f = reinterpret_cast<const float4*>(s)[idx];
  struct B4 { bf16 a, b, c, d; };
  B4 o = { __float2bfloat16(f.x), __float2bfloat16(f.y),
           __float2bfloat16(f.z), __float2bfloat16(f.w) };
  reinterpret_cast<B4*>(d)[idx] = o;
}

// --------------------------------------------------------------- GEMM core
// 128x128 tile, BK=64, v_mfma_f32_32x32x16_bf16 (2382 TF ceiling vs 2075 for
// 16x16). Wave = 64x64 as 2x2 of 32x32. OPERANDS SWAPPED in the MFMA call so
// D = C^T layout: lane owns 4 consecutive n per reg-quad -> packed epilogue.
// LDS XOR swizzle granule g^(r&7): 0 bank conflicts (verified R3/R4).
__device__ __forceinline__ void gemm_tile_acc(
    const bf16* __restrict__ A, const bf16* __restrict__ W,
    bf16* lds_a, bf16* lds_b, int tid, size_t m0, int n0, f32x16v acc[2][2])
{
  const int lane = tid & 63;
  const int wave = tid >> 6;
  const int l31  = lane & 31;
  const int hi   = lane >> 5;
  const int wr   = (wave >> 1) * 64;
  const int wc   = (wave & 1) * 64;

  int srow[4], scol[4];
#pragma unroll
  for (int q = 0; q < 4; ++q) {
    const int s = tid + q * 256;
    srow[q] = s >> 3;
    scol[q] = (((s & 7) ^ (srow[q] & 7)) * 8);
  }

#pragma unroll
  for (int i = 0; i < 2; ++i)
#pragma unroll
    for (int j = 0; j < 2; ++j)
#pragma unroll
      for (int r = 0; r < 16; ++r) acc[i][j][r] = 0.0f;

  for (int k0 = 0; k0 < 768; k0 += 64) {
    __syncthreads();
#pragma unroll
    for (int q = 0; q < 4; ++q)
      GLD_LDS16(A + (m0 + srow[q]) * 768 + k0 + scol[q], &lds_a[(size_t)(tid + q * 256) * 8]);
#pragma unroll
    for (int q = 0; q < 4; ++q)
      GLD_LDS16(W + (size_t)(n0 + srow[q]) * 768 + k0 + scol[q], &lds_b[(size_t)(tid + q * 256) * 8]);
    __syncthreads();

#pragma unroll
    for (int ks = 0; ks < 4; ++ks) {           // k-steps of 16 within BK=64
      const int gl = ks * 2 + hi;              // element granule = k/8 (pre-swizzle)
      bf16x8v av[2], bv[2];
#pragma unroll
      for (int i = 0; i < 2; ++i) {
        const int ra = wr + 32 * i + l31;
        av[i] = *(const bf16x8v*)&lds_a[ra * 64 + ((gl ^ (ra & 7)) * 8)];
      }
#pragma unroll
      for (int j = 0; j < 2; ++j) {
        const int rb = wc + 32 * j + l31;
        bv[j] = *(const bf16x8v*)&lds_b[rb * 64 + ((gl ^ (rb & 7)) * 8)];
      }
#pragma unroll
      for (int i = 0; i < 2; ++i)
#pragma unroll
        for (int j = 0; j < 2; ++j)
          acc[i][j] = __builtin_amdgcn_mfma_f32_32x32x16_bf16(bv[j], av[i], acc[i][j], 0, 0, 0);
    }
  }
}

// Epilogue index helpers: with swapped operands,
//   C row (m) = m0 + wr + 32*i + l31
//   C col (n) = n0 + wc + 32*j + (reg&3) + 8*(reg>>2) + 4*hi   (reg = 4*rr+q)
// -> per (i,j,rr): 4 consecutive cols at nb+8*rr, pack 4 bf16 (8 B) or float4.

// Fused K/V/R GEMM. grid 4608 = chunk(4) x ntile(18) x mm(64), mm fastest.
__global__ __launch_bounds__(256) void gemm_kvr(
    const bf16* __restrict__ A, const bf16* __restrict__ Wcat,
    bf16* __restrict__ Kb, bf16* __restrict__ Vb, bf16* __restrict__ SRb)
{
  __shared__ __align__(16) bf16 lds_a[128 * 64];
  __shared__ __align__(16) bf16 lds_b[128 * 64];
  const int tid = threadIdx.x;
  const int bx = blockIdx.x;
  const int chunk = bx / 1152;
  const int rem   = bx % 1152;
  const int mm    = rem & 63;
  const int nt    = rem >> 6;
  const size_t m0 = (size_t)(chunk * 64 + mm) * 128;
  const int n0 = nt * 128;

  f32x16v acc[2][2];
  gemm_tile_acc(A, Wcat, lds_a, lds_b, tid, m0, n0, acc);

  const int seg   = n0 / 768;
  const int ncol0 = n0 - seg * 768;
  bf16* __restrict__ dst = (seg == 0) ? Kb : (seg == 1) ? Vb : SRb;
  const int lane = tid & 63, wave = tid >> 6;
  const int l31 = lane & 31, hi = lane >> 5;
  const int wr = (wave >> 1) * 64, wc = (wave & 1) * 64;
#pragma unroll
  for (int i = 0; i < 2; ++i) {
    const size_t mrow = m0 + wr + 32 * i + l31;
#pragma unroll
    for (int j = 0; j < 2; ++j) {
      const int nb = ncol0 + wc + 32 * j + 4 * hi;
#pragma unroll
      for (int rr = 0; rr < 4; ++rr) {
        float v0 = acc[i][j][4 * rr + 0], v1 = acc[i][j][4 * rr + 1];
        float v2 = acc[i][j][4 * rr + 2], v3 = acc[i][j][4 * rr + 3];
        if (seg == 2) {
          v0 = 1.0f / (1.0f + __expf(-v0)); v1 = 1.0f / (1.0f + __expf(-v1));
          v2 = 1.0f / (1.0f + __expf(-v2)); v3 = 1.0f / (1.0f + __expf(-v3));
        }
        ushort4 pk = { bfraw(v0), bfraw(v1), bfraw(v2), bfraw(v3) };
        *(ushort4*)&dst[mrow * 768 + nb + 8 * rr] = pk;
      }
    }
  }
}

// Output GEMM: fp32 out. grid 1536 = chunk(4) x ntile(6) x mm(64).
__global__ __launch_bounds__(256) void gemm_out(
    const bf16* __restrict__ A, const bf16* __restrict__ W,
    float* __restrict__ out)
{
  __shared__ __align__(16) bf16 lds_a[128 * 64];
  __shared__ __align__(16) bf16 lds_b[128 * 64];
  const int tid = threadIdx.x;
  const int bx = blockIdx.x;
  const int chunk = bx / 384;
  const int rem   = bx % 384;
  const int mm    = rem & 63;
  const int nt    = rem >> 6;
  const size_t m0 = (size_t)(chunk * 64 + mm) * 128;
  const int n0 = nt * 128;

  f32x16v acc[2][2];
  gemm_tile_acc(A, W, lds_a, lds_b, tid, m0, n0, acc);

  const int lane = tid & 63, wave = tid >> 6;
  const int l31 = lane & 31, hi = lane >> 5;
  const int wr = (wave >> 1) * 64, wc = (wave & 1) * 64;
#pragma unroll
  for (int i = 0; i < 2; ++i) {
    const size_t mrow = m0 + wr + 32 * i + l31;
#pragma unroll
    for (int j = 0; j < 2; ++j) {
      const int nb = n0 + wc + 32 * j + 4 * hi;
#pragma unroll
      for (int rr = 0; rr < 4; ++rr) {
        float4 pk = { acc[i][j][4 * rr + 0], acc[i][j][4 * rr + 1],
                      acc[i][j][4 * rr + 2], acc[i][j][4 * rr + 3] };
        *(float4*)&out[mrow * 768 + nb + 8 * rr] = pk;
      }
    }
  }
}

// ------------------------------------------------------------ WKV chunk scan
// G=128 chunks of L=32. 4 channels/thread. State math fp32.
__global__ void wkv_phaseA(const bf16* __restrict__ K, const bf16* __restrict__ V,
                           const float* __restrict__ sd,
                           float* __restrict__ sA, float* __restrict__ sB, float* __restrict__ sP)
{
  const int idx = blockIdx.x * 256 + threadIdx.x;
  const int c4 = idx % 192;
  const int bg = idx / 192;
  const int g  = bg & 127;
  const int b  = bg >> 7;
  const int c0 = c4 * 4;
  float w[4], aa[4], bb[4], pp[4];
#pragma unroll
  for (int e = 0; e < 4; ++e) {
    w[e] = sd[c0 + e] * (1.0f / 4096.0f);
    aa[e] = 0.f; bb[e] = 0.f; pp[e] = -1e38f;
  }
  const size_t base = ((size_t)b * 4096 + (size_t)g * 32) * 768 + c0;
  const uint2* Kp = (const uint2*)(K + base);
  const uint2* Vp = (const uint2*)(V + base);
#pragma unroll 4
  for (int t = 0; t < 32; ++t) {
    const uint2 ku = Kp[(size_t)t * 192];
    const uint2 vu = Vp[(size_t)t * 192];
    const float kc[4] = { bflo(ku.x), bfhi(ku.x), bflo(ku.y), bfhi(ku.y) };
    const float vc[4] = { bflo(vu.x), bfhi(vu.x), bflo(vu.y), bfhi(vu.y) };
#pragma unroll
    for (int e = 0; e < 4; ++e) {
      const float ww2 = w[e] + pp[e];
      const float p2  = fmaxf(ww2, kc[e]);
      const float e1b = __expf(ww2 - p2);
      const float e2b = __expf(kc[e] - p2);
      aa[e] = e1b * aa[e] + e2b * vc[e];
      bb[e] = e1b * bb[e] + e2b;
      pp[e] = p2;
    }
  }
  const int o = g * 6144 + b * 768 + c0;
#pragma unroll
  for (int e = 0; e < 4; ++e) { sA[o + e] = aa[e]; sB[o + e] = bb[e]; sP[o + e] = pp[e]; }
}

__global__ void wkv_phaseB(const float* __restrict__ sA, const float* __restrict__ sB,
                           const float* __restrict__ sP,
                           float* __restrict__ iA, float* __restrict__ iB, float* __restrict__ iP,
                           const float* __restrict__ sd)
{
  const int bc = blockIdx.x * 256 + threadIdx.x;    // B*C = 6144
  const int c  = bc % 768;
  const float Lw = 32.0f * (sd[c] * (1.0f / 4096.0f));
  float aa = 0.f, bb = 0.f, pp = -1e38f;
  for (int g = 0; g < 128; ++g) {
    const int o = g * 6144 + bc;
    iA[o] = aa; iB[o] = bb; iP[o] = pp;             // state BEFORE chunk g
    const float la = sA[o], lb = sB[o], lp = sP[o];
    const float pd = pp + Lw;
    const float pn = fmaxf(pd, lp);
    const float e0 = __expf(pd - pn);
    const float e1 = __expf(lp - pn);
    aa = e0 * aa + e1 * la;
    bb = e0 * bb + e1 * lb;
    pp = pn;
  }
}

__global__ void wkv_phaseC(const bf16* __restrict__ K, const bf16* __restrict__ V,
                           const bf16* __restrict__ SR,
                           const float* __restrict__ iA, const float* __restrict__ iB,
                           const float* __restrict__ iP,
                           const float* __restrict__ sd, const float* __restrict__ sf,
                           bf16* __restrict__ RY)
{
  const int idx = blockIdx.x * 256 + threadIdx.x;
  const int c4 = idx % 192;
  const int bg = idx / 192;
  const int g  = bg & 127;
  const int b  = bg >> 7;
  const int c0 = c4 * 4;
  const int o = g * 6144 + b * 768 + c0;
  float w[4], u[4], aa[4], bb[4], pp[4];
#pragma unroll
  for (int e = 0; e < 4; ++e) {
    w[e] = sd[c0 + e] * (1.0f / 4096.0f);
    u[e] = sf[c0 + e] * (1.0f / 4096.0f);
    aa[e] = iA[o + e]; bb[e] = iB[o + e]; pp[e] = iP[o + e];
  }
  const size_t base = ((size_t)b * 4096 + (size_t)g * 32) * 768 + c0;
  const uint2* Kp = (const uint2*)(K + base);
  const uint2* Vp = (const uint2*)(V + base);
  const uint2* Sp = (const uint2*)(SR + base);
  uint2* Rp = (uint2*)(RY + base);
#pragma unroll 4
  for (int t = 0; t < 32; ++t) {
    const uint2 ku = Kp[(size_t)t * 192];
    const uint2 vu = Vp[(size_t)t * 192];
    const uint2 su = Sp[(size_t)t * 192];
    const float kc[4] = { bflo(ku.x), bfhi(ku.x), bflo(ku.y), bfhi(ku.y) };
    const float vc[4] = { bflo(vu.x), bfhi(vu.x), bflo(vu.y), bfhi(vu.y) };
    const float sc[4] = { bflo(su.x), bfhi(su.x), bflo(su.y), bfhi(su.y) };
    float y[4];
#pragma unroll
    for (int e = 0; e < 4; ++e) {
      const float ww = u[e] + kc[e];
      const float p  = fmaxf(pp[e], ww);
      const float e1 = __expf(pp[e] - p);
      const float e2 = __expf(ww - p);
      y[e] = (e1 * aa[e] + e2 * vc[e]) / (e1 * bb[e] + e2) * sc[e];
      const float ww2 = w[e] + pp[e];
      const float p2  = fmaxf(ww2, kc[e]);
      const float e1b = __expf(ww2 - p2);
      const float e2b = __expf(kc[e] - p2);
      aa[e] = e1b * aa[e] + e2b * vc[e];
      bb[e] = e1b * bb[e] + e2b;
      pp[e] = p2;
    }
    uint2 r; r.x = packbf(y[0], y[1]); r.y = packbf(y[2], y[3]);
    Rp[(size_t)t * 192] = r;
  }
}

// ---------------------------------------------------------------------------
extern "C" void kernel_launch(void* const* d_in, const int* in_sizes, int n_in,
                              void* d_out, int out_size, void* d_ws, size_t ws_size,
                              hipStream_t stream)
{
  const float* x  = (const float*)d_in[0];
  const float* wk = (const float*)d_in[1];
  const float* wv = (const float*)d_in[2];
  const float* wr = (const float*)d_in[3];
  const float* wo = (const float*)d_in[4];
  const float* sd = (const float*)d_in[5];
  const float* sf = (const float*)d_in[6];
  float* out = (float*)d_out;

  char* ws = (char*)d_ws;
  bf16*  x_bf  = (bf16*) (ws + 0);            // 25165824 * 2
  bf16*  wcat  = (bf16*) (ws + 50331648);     // 2304x768 bf16
  bf16*  wo_bf = (bf16*) (ws + 53870592);
  bf16*  Kb    = (bf16*) (ws + 55050240);     // 25165824 * 2 each
  bf16*  Vb    = (bf16*) (ws + 105381888);
  bf16*  SRb   = (bf16*) (ws + 155713536);
  float* sumA  = (float*)(ws + 206045184);    // 128*6144 floats (3 MB) each
  float* sumB  = (float*)(ws + 209190912);
  float* sumP  = (float*)(ws + 212336640);
  float* iniA  = (float*)(ws + 215482368);
  float* iniB  = (float*)(ws + 218628096);
  float* iniP  = (float*)(ws + 221773824);
  bf16*  ry_bf = x_bf;                        // x dead after gemm_kvr -> alias

  f2b4_all<<<26880, 256, 0, stream>>>(x, wk, wv, wr, wo, x_bf, wcat, wo_bf);

  gemm_kvr<<<4608, 256, 0, stream>>>(x_bf, wcat, Kb, Vb, SRb);

  wkv_phaseA<<<768, 256, 0, stream>>>(Kb, Vb, sd, sumA, sumB, sumP);
  wkv_phaseB<<<24,  256, 0, stream>>>(sumA, sumB, sumP, iniA, iniB, iniP, sd);
  wkv_phaseC<<<768, 256, 0, stream>>>(Kb, Vb, SRb, iniA, iniB, iniP, sd, sf, ry_bf);

  gemm_out<<<1536, 256, 0, stream>>>(ry_bf, wo_bf, out);
}